// Round 5
// baseline (304.767 us; speedup 1.0000x reference)
//
#include <hip/hip_runtime.h>
#include <cstdint>

// Problem constants (from reference setup_inputs)
#define AH 7
#define AW 7
#define AL 7
constexpr int Bc = 2, Cc = 128, Hc = 64, Wc = 64, Lc = 32, Nc = 256;
constexpr int HWL = Hc * Wc * Lc;     // channel stride in feat
constexpr int WL  = Wc * Lc;          // h-plane stride
constexpr int VOL = AH * AW * AL;     // 343, per-channel output volume
constexpr int JK  = AW * AL;          // 49
constexpr int HALF_E = (Cc / 2) * JK; // 3136 elements (c in [0,64))

// One block per (roi n, grid row i), swizzled so all 7 i-siblings of a roi
// land on the SAME XCD (blockIdx % 8 == n % 8) and share the roi subvolume
// in that XCD's L2. Each iteration handles channels c and c+64 for one
// (j,k): spatial weights computed once, 16 independent gathers in flight.
__global__ __launch_bounds__(256)
void roialign3d_v2(const float* __restrict__ feat,
                   const float* __restrict__ rois,
                   const float* __restrict__ scale_p,
                   float* __restrict__ out) {
    const int idx = blockIdx.x;
    const int n = idx & 255;   // idx = i*256 + n  ->  same XCD residue per roi
    const int i = idx >> 8;

    const float scale = scale_p[0];
    const float* r = rois + n * 7;
    const int   bi = (int)r[0];
    const float h1 = r[1] * scale, w1 = r[2] * scale, l1 = r[3] * scale;
    const float h2 = r[4] * scale, w2 = r[5] * scale, l2 = r[6] * scale;

    const float sh = fmaxf(h2 - h1 + 1.0f, 0.0f) * (1.0f / (AH - 1));
    const float sw = fmaxf(w2 - w1 + 1.0f, 0.0f) * (1.0f / (AW - 1));
    const float sl = fmaxf(l2 - l1 + 1.0f, 0.0f) * (1.0f / (AL - 1));

    // h-direction for this block's row i (uniform across block)
    const float gh  = fminf(fmaxf(h1 + sh * (float)i, 0.0f), (float)(Hc - 1));
    const float h0f = floorf(gh);
    const float fh  = gh - h0f;
    const int   h0i = (int)h0f;
    const int   h1i = min(h0i + 1, Hc - 1);
    const float ofh = 1.0f - fh;

    const float* __restrict__ fb  = feat + (size_t)bi * Cc * HWL;
    const float* __restrict__ hp0 = fb + (size_t)h0i * WL; // + c*HWL + w*Lc + l
    const float* __restrict__ hp1 = fb + (size_t)h1i * WL;

    float* __restrict__ outn = out + (size_t)n * Cc * VOL + (size_t)i * JK;

    for (int e = threadIdx.x; e < HALF_E; e += 256) {
        const int k = e % AL;
        const int j = (e / AL) % AW;
        const int c = e / JK;   // 0..63

        const float gw  = fminf(fmaxf(w1 + sw * (float)j, 0.0f), (float)(Wc - 1));
        const float gl  = fminf(fmaxf(l1 + sl * (float)k, 0.0f), (float)(Lc - 1));
        const float w0f = floorf(gw);
        const float l0f = floorf(gl);
        const float fw  = gw - w0f;
        const float fl  = gl - l0f;
        const int   w0i = (int)w0f;
        const int   l0i = (int)l0f;
        const int   w1i = min(w0i + 1, Wc - 1);
        const int   l1i = min(l0i + 1, Lc - 1);

        const size_t cA = (size_t)c * HWL;
        const size_t cB = cA + (size_t)(Cc / 2) * HWL;
        const int r00 = w0i * Lc, r01 = w1i * Lc;

        // 16 independent gathers (channels c and c+64, same spatial taps)
        const float A000 = hp0[cA + r00 + l0i], A001 = hp0[cA + r00 + l1i];
        const float A010 = hp0[cA + r01 + l0i], A011 = hp0[cA + r01 + l1i];
        const float A100 = hp1[cA + r00 + l0i], A101 = hp1[cA + r00 + l1i];
        const float A110 = hp1[cA + r01 + l0i], A111 = hp1[cA + r01 + l1i];
        const float B000 = hp0[cB + r00 + l0i], B001 = hp0[cB + r00 + l1i];
        const float B010 = hp0[cB + r01 + l0i], B011 = hp0[cB + r01 + l1i];
        const float B100 = hp1[cB + r00 + l0i], B101 = hp1[cB + r00 + l1i];
        const float B110 = hp1[cB + r01 + l0i], B111 = hp1[cB + r01 + l1i];

        const float ofl = 1.0f - fl, ofw = 1.0f - fw;
        const float a00 = A000 * ofl + A001 * fl;
        const float a01 = A010 * ofl + A011 * fl;
        const float a10 = A100 * ofl + A101 * fl;
        const float a11 = A110 * ofl + A111 * fl;
        const float b00 = B000 * ofl + B001 * fl;
        const float b01 = B010 * ofl + B011 * fl;
        const float b10 = B100 * ofl + B101 * fl;
        const float b11 = B110 * ofl + B111 * fl;

        const float aa0 = a00 * ofw + a01 * fw;
        const float aa1 = a10 * ofw + a11 * fw;
        const float bb0 = b00 * ofw + b01 * fw;
        const float bb1 = b10 * ofw + b11 * fw;

        const float resA = aa0 * ofh + aa1 * fh;
        const float resB = bb0 * ofh + bb1 * fh;

        const size_t oA = (size_t)c * VOL + (size_t)(j * AL + k);
        outn[oA] = resA;
        outn[oA + (size_t)(Cc / 2) * VOL] = resB;
    }
}

extern "C" void kernel_launch(void* const* d_in, const int* in_sizes, int n_in,
                              void* d_out, int out_size, void* d_ws, size_t ws_size,
                              hipStream_t stream) {
    const float* feat    = (const float*)d_in[0];
    const float* rois    = (const float*)d_in[1];
    const float* scale_p = (const float*)d_in[2];
    float* out = (float*)d_out;

    dim3 grid(Nc * AH);
    dim3 block(256);
    roialign3d_v2<<<grid, block, 0, stream>>>(feat, rois, scale_p, out);
}

// Round 13
// 267.326 us; speedup vs baseline: 1.1401x; 1.1401x over previous
//
#include <hip/hip_runtime.h>
#include <cstdint>

// Problem constants (from reference setup_inputs)
#define AH 7
#define AW 7
#define AL 7
constexpr int Cc = 128, Hc = 64, Wc = 64, Lc = 32, Nc = 256;
constexpr int HWL = Hc * Wc * Lc;   // channel stride in feat
constexpr int WL  = Wc * Lc;        // h-plane stride
constexpr int VOL = AH * AW * AL;   // 343
constexpr int JK  = AW * AL;        // 49

constexpr int CHUNK = 8;                    // channels staged per chunk
constexpr int ROWS  = CHUNK * 2 * AW * 2;   // 224 L-rows per chunk: (cl,hsel,j,wsel)
constexpr int RPAD  = 36;                   // padded row length in floats (16B-aligned, bank-spread)

// Block per (roi n, grid row i) in natural order n*7+i (temporal sibling locality).
// Phase 1 per chunk: stage the 28 needed 32-float L-rows for 8 channels into LDS
// with fully-coalesced float4 loads (row addresses are block-uniform geometry).
// Phase 2: trilinear interp reads LDS only; stores coalesce in 49-float runs.
__global__ __launch_bounds__(256)
void roialign3d_v3(const float* __restrict__ feat,
                   const float* __restrict__ rois,
                   const float* __restrict__ scale_p,
                   float* __restrict__ out) {
    __shared__ float lds[ROWS * RPAD];      // 224*36*4 = 32256 B -> 5 blocks/CU

    const int idx = blockIdx.x;
    const int n = idx / AH;
    const int i = idx % AH;

    const float scale = scale_p[0];
    const float* r = rois + n * 7;
    const int   bi = (int)r[0];
    const float h1 = r[1] * scale, w1 = r[2] * scale, l1 = r[3] * scale;
    const float h2 = r[4] * scale, w2 = r[5] * scale, l2 = r[6] * scale;

    const float sh = fmaxf(h2 - h1 + 1.0f, 0.0f) * (1.0f / (AH - 1));
    const float sw = fmaxf(w2 - w1 + 1.0f, 0.0f) * (1.0f / (AW - 1));
    const float sl = fmaxf(l2 - l1 + 1.0f, 0.0f) * (1.0f / (AL - 1));

    // h-direction (uniform across block)
    const float gh  = fminf(fmaxf(h1 + sh * (float)i, 0.0f), (float)(Hc - 1));
    const int   h0i = (int)gh;              // gh >= 0 -> trunc == floor
    const float fh  = gh - (float)h0i;
    const int   h1i = min(h0i + 1, Hc - 1);
    const float ofh = 1.0f - fh;

    const float* __restrict__ fb = feat + (size_t)bi * Cc * HWL;
    float* __restrict__ outni = out + (size_t)n * Cc * VOL + (size_t)i * JK;

    for (int c0 = 0; c0 < Cc; c0 += CHUNK) {
        // ---- Phase 1: coalesced staging. 224 rows * 8 float4 = 1792 = 7*256 ----
        #pragma unroll
        for (int p = 0; p < 7; ++p) {
            const int q    = (int)threadIdx.x + p * 256;  // 0..1791
            const int l4   = q & 7;                       // float4 slot in row
            const int row  = q >> 3;                      // 0..223
            const int cl   = row / 28;
            const int rr   = row % 28;
            const int hsel = rr / 14;
            const int rr2  = rr % 14;
            const int j    = rr2 >> 1;
            const int wsel = rr2 & 1;

            const float gw = fminf(fmaxf(w1 + sw * (float)j, 0.0f), (float)(Wc - 1));
            int wv = (int)gw;
            if (wsel) wv = min(wv + 1, Wc - 1);
            const int hv = hsel ? h1i : h0i;

            const float4 v = *(const float4*)(fb + (size_t)(c0 + cl) * HWL
                                              + hv * WL + wv * Lc + l4 * 4);
            *(float4*)(&lds[row * RPAD + l4 * 4]) = v;
        }
        __syncthreads();

        // ---- Phase 2: interp from LDS. 8 ch * 49 = 392 elements ----
        #pragma unroll
        for (int pass = 0; pass < 2; ++pass) {
            const int e = (int)threadIdx.x + pass * 256;
            if (e < CHUNK * JK) {
                const int k  = e % 7;
                const int j  = (e / 7) % 7;
                const int cl = e / 49;

                const float gw  = fminf(fmaxf(w1 + sw * (float)j, 0.0f), (float)(Wc - 1));
                const float gl  = fminf(fmaxf(l1 + sl * (float)k, 0.0f), (float)(Lc - 1));
                const float fw  = gw - floorf(gw);
                const int   l0i = (int)gl;
                const float fl  = gl - (float)l0i;
                const int   l1i = min(l0i + 1, Lc - 1);

                const int rbase = cl * 28 + j * 2;      // + hsel*14 + wsel
                const float* r00 = &lds[(rbase +  0) * RPAD];
                const float* r01 = &lds[(rbase +  1) * RPAD];
                const float* r10 = &lds[(rbase + 14) * RPAD];
                const float* r11 = &lds[(rbase + 15) * RPAD];

                const float ofl = 1.0f - fl, ofw = 1.0f - fw;
                const float a00 = r00[l0i] * ofl + r00[l1i] * fl;
                const float a01 = r01[l0i] * ofl + r01[l1i] * fl;
                const float a10 = r10[l0i] * ofl + r10[l1i] * fl;
                const float a11 = r11[l0i] * ofl + r11[l1i] * fl;

                const float b0 = a00 * ofw + a01 * fw;
                const float b1 = a10 * ofw + a11 * fw;

                outni[(size_t)(c0 + cl) * VOL + j * AL + k] = b0 * ofh + b1 * fh;
            }
        }
        __syncthreads();
    }
}

extern "C" void kernel_launch(void* const* d_in, const int* in_sizes, int n_in,
                              void* d_out, int out_size, void* d_ws, size_t ws_size,
                              hipStream_t stream) {
    const float* feat    = (const float*)d_in[0];
    const float* rois    = (const float*)d_in[1];
    const float* scale_p = (const float*)d_in[2];
    float* out = (float*)d_out;

    dim3 grid(Nc * AH);
    dim3 block(256);
    roialign3d_v3<<<grid, block, 0, stream>>>(feat, rois, scale_p, out);
}